// Round 8
// baseline (211.898 us; speedup 1.0000x reference)
//
#include <hip/hip_runtime.h>
#include <math.h>

#define NQ 4
#define NL 2
#define DIM 16          // 2^NQ
#define BATCH 16
#define CH 256
#define HW 16384        // 128*128
#define NBLK 512        // 2 blocks/CU on 256 CUs -- all co-resident (pigeonhole)
#define SPB 8           // slices (b,c) per block, all same b

typedef float floatx4 __attribute__((ext_vector_type(4)));

// Persistent fused kernel: pool -> software grid barrier -> gate -> scale.
// Residency: slices 0,1 of each block's 8 stay in VGPRs (128 regs) across the
// barrier, so phase 3 re-reads only 6/8 of x. __launch_bounds__(256,2) caps
// VGPRs at 256 -> every CU fits 2 blocks -> all 512 blocks co-resident ->
// the atomic-counter barrier cannot deadlock.
__global__ __launch_bounds__(256, 2) void fused_all(
    const float* __restrict__ x,
    const float* __restrict__ enc_w,   // [NQ, CH]
    const float* __restrict__ enc_b,   // [NQ]
    const float* __restrict__ qw,      // [NL, NQ, 3]
    const float* __restrict__ proj_w,  // [CH, NQ]
    const float* __restrict__ proj_b,  // [CH]
    float* __restrict__ out,
    float* __restrict__ pooled,        // ws: [BATCH*CH]
    unsigned* __restrict__ ctr)        // ws: barrier counter (memset 0 per call)
{
    const int tid = threadIdx.x;
    const int slice0 = blockIdx.x * SPB;    // 8 consecutive (b,c), same b
    const int b = slice0 >> 8;

    __shared__ float partial[4];
    __shared__ float sz[NQ];
    __shared__ float sevs[NQ];
    __shared__ float sgate[SPB];

    // ---------------- Phase 1: pool ----------------
    floatx4 v0[16], v1[16];
    {
        const floatx4* x0 = (const floatx4*)(x + (size_t)(slice0 + 0) * HW);
        const floatx4* x1 = (const floatx4*)(x + (size_t)(slice0 + 1) * HW);
#pragma unroll
        for (int k = 0; k < 16; ++k) v0[k] = x0[tid + k * 256];
#pragma unroll
        for (int k = 0; k < 16; ++k) v1[k] = x1[tid + k * 256];
        float s0 = 0.f, s1 = 0.f;
#pragma unroll
        for (int k = 0; k < 16; ++k) { s0 += v0[k].x + v0[k].y + v0[k].z + v0[k].w; }
#pragma unroll
        for (int k = 0; k < 16; ++k) { s1 += v1[k].x + v1[k].y + v1[k].z + v1[k].w; }
#pragma unroll
        for (int off = 32; off > 0; off >>= 1) s0 += __shfl_down(s0, off, 64);
        if ((tid & 63) == 0) partial[tid >> 6] = s0;
        __syncthreads();
        if (tid == 0)
            pooled[slice0 + 0] = (partial[0] + partial[1] + partial[2] + partial[3]) * (1.f / HW);
        __syncthreads();
#pragma unroll
        for (int off = 32; off > 0; off >>= 1) s1 += __shfl_down(s1, off, 64);
        if ((tid & 63) == 0) partial[tid >> 6] = s1;
        __syncthreads();
        if (tid == 0)
            pooled[slice0 + 1] = (partial[0] + partial[1] + partial[2] + partial[3]) * (1.f / HW);
        __syncthreads();
    }
    for (int s = 2; s < SPB; ++s) {
        const floatx4* xp = (const floatx4*)(x + (size_t)(slice0 + s) * HW);
        float acc = 0.f;
#pragma unroll
        for (int k = 0; k < 16; ++k) {
            floatx4 t = xp[tid + k * 256];
            acc += t.x + t.y + t.z + t.w;
        }
#pragma unroll
        for (int off = 32; off > 0; off >>= 1) acc += __shfl_down(acc, off, 64);
        if ((tid & 63) == 0) partial[tid >> 6] = acc;
        __syncthreads();
        if (tid == 0)
            pooled[slice0 + s] = (partial[0] + partial[1] + partial[2] + partial[3]) * (1.f / HW);
        __syncthreads();
    }

    // ---------------- Grid barrier (all 512 blocks co-resident) ----------------
    __syncthreads();
    if (tid == 0) {
        __threadfence();   // release pooled[] to device scope (cross-XCD)
        __hip_atomic_fetch_add(ctr, 1u, __ATOMIC_ACQ_REL, __HIP_MEMORY_SCOPE_AGENT);
        while (__hip_atomic_load(ctr, __ATOMIC_ACQUIRE, __HIP_MEMORY_SCOPE_AGENT) < (unsigned)NBLK)
            __builtin_amdgcn_s_sleep(8);
        __threadfence();   // acquire
    }
    __syncthreads();

    // ---------------- Phase 2: gate (redundant per block) ----------------
    {
        const int q = tid >> 6, lane = tid & 63;
        const float* prow = pooled + b * CH;
        float acc = 0.f;
#pragma unroll
        for (int j = 0; j < 4; ++j) {
            const int c = lane * 4 + j;
            acc += prow[c] * enc_w[q * CH + c];
        }
#pragma unroll
        for (int off = 32; off > 0; off >>= 1) acc += __shfl_down(acc, off, 64);
        if (lane == 0) sz[q] = tanhf(acc + enc_b[q]);
    }
    __syncthreads();

    if (tid == 0) {
        float re[DIM], im[DIM];
#pragma unroll
        for (int i = 0; i < DIM; ++i) { re[i] = 0.f; im[i] = 0.f; }
        re[0] = 1.f;

        // AngleEmbedding: RY(z_w) on wire w (wire 0 = MSB)
        for (int w = 0; w < NQ; ++w) {
            const float a = sz[w] * 0.5f;
            const float cc = cosf(a), ss = sinf(a);
            const int m = 1 << (3 - w);
#pragma unroll
            for (int i = 0; i < DIM; ++i) {
                if (i & m) continue;
                const int j = i | m;
                const float r0 = cc * re[i] - ss * re[j];
                const float i0 = cc * im[i] - ss * im[j];
                const float r1 = ss * re[i] + cc * re[j];
                const float i1 = ss * im[i] + cc * im[j];
                re[i] = r0; im[i] = i0; re[j] = r1; im[j] = i1;
            }
        }
        // StronglyEntanglingLayers
        for (int l = 0; l < NL; ++l) {
            for (int w = 0; w < NQ; ++w) {
                const float phi = qw[(l * NQ + w) * 3 + 0];
                const float th  = qw[(l * NQ + w) * 3 + 1];
                const float om  = qw[(l * NQ + w) * 3 + 2];
                const float ct = cosf(0.5f * th), st = sinf(0.5f * th);
                const float am = -0.5f * (phi + om);
                const float ad =  0.5f * (phi - om);
                const float emr = cosf(am), emi = sinf(am);
                const float edr = cosf(ad), edi = sinf(ad);
                const float u00r =  emr * ct, u00i =  emi * ct;
                const float u01r = -edr * st, u01i = -edi * st;
                const float u10r =  edr * st, u10i = -edi * st;
                const float u11r =  emr * ct, u11i = -emi * ct;
                const int m = 1 << (3 - w);
#pragma unroll
                for (int i = 0; i < DIM; ++i) {
                    if (i & m) continue;
                    const int j = i | m;
                    const float ar = re[i], ai = im[i], br = re[j], bi = im[j];
                    re[i] = u00r * ar - u00i * ai + u01r * br - u01i * bi;
                    im[i] = u00r * ai + u00i * ar + u01r * bi + u01i * br;
                    re[j] = u10r * ar - u10i * ai + u11r * br - u11i * bi;
                    im[j] = u10r * ai + u10i * ar + u11r * bi + u11i * br;
                }
            }
            const int r = (l % (NQ - 1)) + 1;
            for (int w = 0; w < NQ; ++w) {
                const int t = (w + r) % NQ;
                const int cm = 1 << (3 - w);
                const int tm = 1 << (3 - t);
#pragma unroll
                for (int i = 0; i < DIM; ++i) {
                    if ((i & cm) && !(i & tm)) {
                        const int j = i | tm;
                        float tr = re[i]; re[i] = re[j]; re[j] = tr;
                        float ti = im[i]; im[i] = im[j]; im[j] = ti;
                    }
                }
            }
        }
        float p[DIM];
#pragma unroll
        for (int i = 0; i < DIM; ++i) p[i] = re[i] * re[i] + im[i] * im[i];
        for (int w = 0; w < NQ; ++w) {
            const int m = 1 << (3 - w);
            float ev = 0.f;
#pragma unroll
            for (int i = 0; i < DIM; ++i) ev += (i & m) ? -p[i] : p[i];
            sevs[w] = ev;
        }
    }
    __syncthreads();

    if (tid < SPB) {
        const int c = (slice0 & 255) + tid;
        const float acc = sevs[0] * proj_w[c * NQ + 0] + sevs[1] * proj_w[c * NQ + 1] +
                          sevs[2] * proj_w[c * NQ + 2] + sevs[3] * proj_w[c * NQ + 3] +
                          proj_b[c];
        sgate[tid] = 1.f + 1.f / (1.f + expf(-acc));
    }
    __syncthreads();

    // ---------------- Phase 3: scale ----------------
    // resident slices: no re-read
    {
        floatx4* o0 = (floatx4*)(out + (size_t)(slice0 + 0) * HW);
        floatx4* o1 = (floatx4*)(out + (size_t)(slice0 + 1) * HW);
        const float g0 = sgate[0], g1 = sgate[1];
#pragma unroll
        for (int k = 0; k < 16; ++k) {
            floatx4 t = v0[k] * g0;
            __builtin_nontemporal_store(t, &o0[tid + k * 256]);
        }
#pragma unroll
        for (int k = 0; k < 16; ++k) {
            floatx4 t = v1[k] * g1;
            __builtin_nontemporal_store(t, &o1[tid + k * 256]);
        }
    }
    // streamed slices
    for (int s = 2; s < SPB; ++s) {
        const float g = sgate[s];
        const floatx4* xp = (const floatx4*)(x + (size_t)(slice0 + s) * HW);
        floatx4* op = (floatx4*)(out + (size_t)(slice0 + s) * HW);
        floatx4 t[16];
#pragma unroll
        for (int k = 0; k < 16; ++k) t[k] = xp[tid + k * 256];
#pragma unroll
        for (int k = 0; k < 16; ++k) {
            floatx4 w = t[k] * g;
            __builtin_nontemporal_store(w, &op[tid + k * 256]);
        }
    }
}

extern "C" void kernel_launch(void* const* d_in, const int* in_sizes, int n_in,
                              void* d_out, int out_size, void* d_ws, size_t ws_size,
                              hipStream_t stream) {
    const float* x      = (const float*)d_in[0];
    const float* enc_w  = (const float*)d_in[1];
    const float* enc_b  = (const float*)d_in[2];
    const float* qw     = (const float*)d_in[3];
    const float* proj_w = (const float*)d_in[4];
    const float* proj_b = (const float*)d_in[5];
    float* out = (float*)d_out;

    float* pooled = (float*)d_ws;                       // [4096]
    unsigned* ctr = (unsigned*)(pooled + BATCH * CH);   // barrier counter

    hipMemsetAsync(ctr, 0, sizeof(unsigned), stream);   // reset barrier each call
    fused_all<<<NBLK, 256, 0, stream>>>(x, enc_w, enc_b, qw, proj_w, proj_b,
                                        out, pooled, ctr);
}